// Round 8
// baseline (302.775 us; speedup 1.0000x reference)
//
#include <hip/hip_runtime.h>

// VQ nearest-embedding, split-fp16 MFMA (3 terms: hh, hl, lh - validated R5-R7).
// R8: force total regs <= 128 (launch_bounds(512,4)) so 2 blocks/CU co-reside
// (R3/R5/R6/R7 evidence: occupancy == f(VGPR+64 AGPR)); all in-loop addressing
// reduced to pointer increments (e16 layout linear in dt; kt jump constant).
// emb pre-split once into fp16 hi/lo planes in donated d_out rows 4..19/batch.

typedef __attribute__((ext_vector_type(8))) _Float16 half8v;  // 8 fp16 = 4 VGPRs
typedef __attribute__((ext_vector_type(16))) float floatx16;  // 32x32 acc
typedef unsigned int uint;
typedef unsigned short ushort;
typedef unsigned long long ull;

#define DD 256
#define KK 2048
#define SS 1024
#define NN 32768
#define MT 128      // latents per block
#define NTT 256     // codes per kt tile
#define KSPLIT 2    // codebook halves
#define LDA 24      // A LDS row stride (ushorts): 48 B, even bank spread for b128
#define WIN 524288  // ushorts per donated window stride (1 batch of d_out)
#define MFMA_F16 __builtin_amdgcn_mfma_f32_32x32x16_f16

union HU { _Float16 f; ushort u; };

__device__ __forceinline__ void split16(float v, ushort& h, ushort& l) {
    HU a, b;
    a.f = (_Float16)v;                       // RNE
    b.f = (_Float16)(v - (float)a.f);
    h = a.u; l = b.u;
}

__device__ __forceinline__ uint mono(float s) {   // order-preserving f32 -> u32
    uint b = __float_as_uint(s);
    return b ^ ((b & 0x80000000u) ? 0xFFFFFFFFu : 0x80000000u);
}

__device__ __forceinline__ void glds16(const ushort* g, ushort* l) {
    __builtin_amdgcn_global_load_lds(
        (const __attribute__((address_space(1))) void*)g,
        (__attribute__((address_space(3))) void*)l, 16, 0, 0);
}

// Fused: split emb -> fp16 hi/lo planes (donated d_out rows 4..19 of each
// batch) + hn[k] = 0.5*||e_k||^2. Thread per code k; e16 rows are
// code-major (256 d contiguous) so each thread writes its own 512-B row.
__global__ __launch_bounds__(256) void prep_e(const float* __restrict__ emb,
                                              ushort* __restrict__ e16,
                                              float* __restrict__ hn) {
    const uint k = blockIdx.x * 256 + threadIdx.x;   // 2048 threads
    const uint areaH = (k >> 7) * WIN + 8192u + (k & 127u) * 256u;
    const uint areaL = areaH + 16u * WIN;
    float a = 0.f;
#pragma unroll 4
    for (int dg = 0; dg < 32; ++dg) {
        ushort h[8], l[8];
#pragma unroll
        for (int i = 0; i < 8; ++i) {
            float v = emb[(size_t)(dg * 8 + i) * KK + k];
            a += v * v;
            split16(v, h[i], l[i]);
        }
        uint4 t;
        t.x = (uint)h[0] | ((uint)h[1] << 16);
        t.y = (uint)h[2] | ((uint)h[3] << 16);
        t.z = (uint)h[4] | ((uint)h[5] << 16);
        t.w = (uint)h[6] | ((uint)h[7] << 16);
        *reinterpret_cast<uint4*>(&e16[areaH + dg * 8]) = t;
        t.x = (uint)l[0] | ((uint)l[1] << 16);
        t.y = (uint)l[2] | ((uint)l[3] << 16);
        t.z = (uint)l[4] | ((uint)l[5] << 16);
        t.w = (uint)l[6] | ((uint)l[7] << 16);
        *reinterpret_cast<uint4*>(&e16[areaL + dg * 8]) = t;
    }
    hn[k] = 0.5f * a;
}

__global__ __launch_bounds__(512, 4) void vq_fused(
        const float* __restrict__ x, const ushort* __restrict__ e16,
        const float* __restrict__ hn, float* __restrict__ out) {
    __shared__ ushort Ah[2][MT * LDA], Al[2][MT * LDA];   // 24 KB total
    __shared__ ushort Bh[2][NTT * 16], Bl[2][NTT * 16];   // 32 KB total
    __shared__ float sv[4][MT];                            // 2 KB
    __shared__ int   sc[4][MT];                            // 2 KB

    const int tid = threadIdx.x;
    const int lane = tid & 63;
    const int wid = tid >> 6;          // 8 waves: 2(m) x 4(n)
    const int colk = lane & 31;
    const int half = lane >> 5;
    const int wm = (wid & 1) * 64;
    const int wn = (wid >> 1) * 64;

    const int base_n = blockIdx.x * MT;
    const int ks = blockIdx.y;
    const uint kbase = ks * (KK / KSPLIT);    // 0 or 1024
    const int bq = base_n >> 10;
    const int sb = base_n & (SS - 1);

    // A staging: 512 threads stage 128 latents x 16 d
    const int lat_a = tid & 127;
    const int dqa = (tid >> 7) * 4;
    const float* xb = x + ((size_t)bq * DD + dqa) * SS + sb + lat_a;

    // B staging via glds: wave -> plane pB, code groups cc0, cc1
    const uint pB = wid & 1;
    const uint c0B = (wid >> 1) * 64;
    const uint codeB = (lane >> 1);                     // code within 32-group
    const uint hB = (lane & 1) ^ ((lane >> 3) & 1);     // swizzled half

    // per-lane glds source pointers (ushort units), chunk-0 position
    const uint code0 = kbase + c0B + codeB;
    const uint code1 = code0 + 32;
    const ushort* gp0 = e16 + (pB * 16u + (code0 >> 7)) * WIN + 8192u
                        + (code0 & 127u) * 256u + hB * 8u;
    const ushort* gp1 = e16 + (pB * 16u + (code1 >> 7)) * WIN + 8192u
                        + (code1 & 127u) * 256u + hB * 8u;

    floatx16 acc[2][2];
#pragma unroll
    for (int i = 0; i < 2; ++i)
#pragma unroll
        for (int j = 0; j < 2; ++j) acc[i][j] = (floatx16)(0.0f);

    float bestv[2][16];
    int bestc[2][16];
#pragma unroll
    for (int t = 0; t < 2; ++t)
#pragma unroll
        for (int r = 0; r < 16; ++r) { bestv[t][r] = 3.4e38f; bestc[t][r] = 0; }

    // ---- preload chunk 0 (kt=0, dt=0) into buffer 0 ----
    {
        ushort* bp = pB ? &Bl[0][0] : &Bh[0][0];
        glds16(gp0, bp + c0B * 16);
        glds16(gp1, bp + (c0B + 32) * 16);
        float fa[4];
#pragma unroll
        for (int i = 0; i < 4; ++i) fa[i] = xb[(size_t)i * SS];
        ushort h[4], l[4];
#pragma unroll
        for (int i = 0; i < 4; ++i) split16(fa[i], h[i], l[i]);
        uint2 w;
        w.x = (uint)h[0] | ((uint)h[1] << 16);
        w.y = (uint)h[2] | ((uint)h[3] << 16);
        *reinterpret_cast<uint2*>(&Ah[0][lat_a * LDA + dqa]) = w;
        w.x = (uint)l[0] | ((uint)l[1] << 16);
        w.y = (uint)l[2] | ((uint)l[3] << 16);
        *reinterpret_cast<uint2*>(&Al[0][lat_a * LDA + dqa]) = w;
    }
    // advance to chunk 1 (dt=16)
    gp0 += 16; gp1 += 16;
    const float* xa = xb + 16 * SS;
    __syncthreads();

    for (int c = 0; c < 64; ++c) {          // 4 kt x 16 dt chunks (K=16 each)
        const int cur = c & 1, nxt = cur ^ 1;
        float fa[4];
        // ---- issue chunk c+1's B glds + A loads (in flight during MFMA) ----
        if (c < 63) {
            ushort* bp = pB ? &Bl[nxt][0] : &Bh[nxt][0];
            glds16(gp0, bp + c0B * 16);
            glds16(gp1, bp + (c0B + 32) * 16);
#pragma unroll
            for (int i = 0; i < 4; ++i) fa[i] = xa[(size_t)i * SS];
            // advance pointers to chunk c+2
            if ((c & 15) == 14) {           // chunk c+1 was last dt of its kt
                gp0 += 1048576 - 240; gp1 += 1048576 - 240;
                xa -= 240 * SS;
            } else {
                gp0 += 16; gp1 += 16;
                xa += 16 * SS;
            }
        }
        // ---- fragments from current buffer + 12 MFMA (3 terms x 2x2) ----
        const int foA = colk * LDA + half * 8;
        const int hsw = (half ^ ((colk >> 2) & 1)) * 8;   // B read swizzle
        half8v ah0 = *reinterpret_cast<const half8v*>(&Ah[cur][foA + wm * LDA]);
        half8v ah1 = *reinterpret_cast<const half8v*>(&Ah[cur][foA + (wm + 32) * LDA]);
        half8v al0 = *reinterpret_cast<const half8v*>(&Al[cur][foA + wm * LDA]);
        half8v al1 = *reinterpret_cast<const half8v*>(&Al[cur][foA + (wm + 32) * LDA]);
        half8v bh0 = *reinterpret_cast<const half8v*>(&Bh[cur][(wn + colk) * 16 + hsw]);
        half8v bh1 = *reinterpret_cast<const half8v*>(&Bh[cur][(wn + 32 + colk) * 16 + hsw]);
        half8v bl0 = *reinterpret_cast<const half8v*>(&Bl[cur][(wn + colk) * 16 + hsw]);
        half8v bl1 = *reinterpret_cast<const half8v*>(&Bl[cur][(wn + 32 + colk) * 16 + hsw]);

        acc[0][0] = MFMA_F16(ah0, bh0, acc[0][0], 0, 0, 0);
        acc[0][0] = MFMA_F16(ah0, bl0, acc[0][0], 0, 0, 0);
        acc[0][0] = MFMA_F16(al0, bh0, acc[0][0], 0, 0, 0);

        acc[0][1] = MFMA_F16(ah0, bh1, acc[0][1], 0, 0, 0);
        acc[0][1] = MFMA_F16(ah0, bl1, acc[0][1], 0, 0, 0);
        acc[0][1] = MFMA_F16(al0, bh1, acc[0][1], 0, 0, 0);

        acc[1][0] = MFMA_F16(ah1, bh0, acc[1][0], 0, 0, 0);
        acc[1][0] = MFMA_F16(ah1, bl0, acc[1][0], 0, 0, 0);
        acc[1][0] = MFMA_F16(al1, bh0, acc[1][0], 0, 0, 0);

        acc[1][1] = MFMA_F16(ah1, bh1, acc[1][1], 0, 0, 0);
        acc[1][1] = MFMA_F16(ah1, bl1, acc[1][1], 0, 0, 0);
        acc[1][1] = MFMA_F16(al1, bh1, acc[1][1], 0, 0, 0);

        // ---- convert prefetched A -> write NEXT buffer (overlaps MFMA) ----
        if (c < 63) {
            ushort h[4], l[4];
#pragma unroll
            for (int i = 0; i < 4; ++i) split16(fa[i], h[i], l[i]);
            uint2 w;
            w.x = (uint)h[0] | ((uint)h[1] << 16);
            w.y = (uint)h[2] | ((uint)h[3] << 16);
            *reinterpret_cast<uint2*>(&Ah[nxt][lat_a * LDA + dqa]) = w;
            w.x = (uint)l[0] | ((uint)l[1] << 16);
            w.y = (uint)l[2] | ((uint)l[3] << 16);
            *reinterpret_cast<uint2*>(&Al[nxt][lat_a * LDA + dqa]) = w;
        }
        // ---- per-kt epilogue: running per-lane argmin, reset acc ----
        if ((c & 15) == 15) {
            const int kt = c >> 4;
            const int cd0 = kbase + kt * NTT + wn + colk;
            const int cd1 = cd0 + 32;
            const float h0 = hn[cd0];
            const float h1 = hn[cd1];
#pragma unroll
            for (int tm = 0; tm < 2; ++tm) {
#pragma unroll
                for (int r = 0; r < 16; ++r) {
                    float s0 = h0 - acc[tm][0][r];
                    float s1 = h1 - acc[tm][1][r];
                    float v = s0; int cd = cd0;
                    if (s1 < s0) { v = s1; cd = cd1; }   // strict <: smaller code wins
                    if (v < bestv[tm][r]) { bestv[tm][r] = v; bestc[tm][r] = cd; }
                    acc[tm][0][r] = 0.f;
                    acc[tm][1][r] = 0.f;
                }
            }
        }
        __syncthreads();   // single barrier/chunk: drains glds + A writes
    }

    // ---- cross-lane argmin over the 32 colk lanes ----
#pragma unroll
    for (int tm = 0; tm < 2; ++tm) {
#pragma unroll
        for (int r = 0; r < 16; ++r) {
            float v = bestv[tm][r];
            int cd = bestc[tm][r];
#pragma unroll
            for (int mk = 1; mk < 32; mk <<= 1) {
                float ov = __shfl_xor(v, mk);
                int oc = __shfl_xor(cd, mk);
                if (ov < v || (ov == v && oc < cd)) { v = ov; cd = oc; }
            }
            if (colk == 0) {
                const int row = (r & 3) + 8 * (r >> 2) + 4 * half;  // verified C/D map
                sv[wid >> 1][wm + tm * 32 + row] = v;
                sc[wid >> 1][wm + tm * 32 + row] = cd;
            }
        }
    }
    __syncthreads();
    // ---- combine 4 n-wave groups, pack u64 key, write to OWN out rows ----
    if (tid < MT) {
        float v = sv[0][tid]; int cd = sc[0][tid];
#pragma unroll
        for (int g = 1; g < 4; ++g) {
            float ov = sv[g][tid]; int oc = sc[g][tid];
            if (ov < v || (ov == v && oc < cd)) { v = ov; cd = oc; }
        }
        ull key = (((ull)mono(v)) << 32) | (uint)cd;
        const int row = 2 * ks + (tid >> 6);     // rows 0..3 (outside e16 rows 4..19)
        ull* p = reinterpret_cast<ull*>(out + ((size_t)(bq * DD + row) * SS + sb));
        p[tid & 63] = key;
    }
}

__global__ __launch_bounds__(512) void gather_kernel(
        const float* __restrict__ emb, float* __restrict__ out) {
    __shared__ int bc[MT];
    const int tid = threadIdx.x;
    const int base_n = blockIdx.x * MT;
    const int bq = base_n >> 10;
    const int sb = base_n & (SS - 1);
    if (tid < MT) {
        const int r = tid >> 6;
        const int cq = tid & 63;
        const ull* p0 = reinterpret_cast<const ull*>(
                out + ((size_t)(bq * DD + r) * SS + sb));
        const ull* p1 = reinterpret_cast<const ull*>(
                out + ((size_t)(bq * DD + 2 + r) * SS + sb));
        ull k0 = p0[cq], k1 = p1[cq];
        ull kb = k0 < k1 ? k0 : k1;       // min score, tie -> smaller code
        bc[tid] = (int)(uint)(kb & 0xFFFFFFFFull);
    }
    __syncthreads();
    {
        const int mq = tid & 31;     // float4 group along m
        const int dg = tid >> 5;     // 0..15, 16 d's each
        const int k0 = bc[mq * 4 + 0];
        const int k1 = bc[mq * 4 + 1];
        const int k2 = bc[mq * 4 + 2];
        const int k3 = bc[mq * 4 + 3];
#pragma unroll 4
        for (int dd = 0; dd < 16; ++dd) {
            const int d = dg * 16 + dd;
            const float* er = emb + (size_t)d * KK;
            float4 o = make_float4(er[k0], er[k1], er[k2], er[k3]);
            reinterpret_cast<float4*>(&out[((size_t)bq * DD + d) * SS + sb])[mq] = o;
        }
    }
}

extern "C" void kernel_launch(void* const* d_in, const int* in_sizes, int n_in,
                              void* d_out, int out_size, void* d_ws, size_t ws_size,
                              hipStream_t stream) {
    const float* x = (const float*)d_in[0];     // (32,256,32,32)
    const float* emb = (const float*)d_in[1];   // (256,2048)
    float* out = (float*)d_out;
    float* hn = (float*)d_ws;                   // 8 KB (proven safe)

    hipLaunchKernelGGL(prep_e, dim3(KK / 256), dim3(256), 0, stream,
                       emb, (ushort*)d_out, hn);
    hipLaunchKernelGGL(vq_fused, dim3(NN / MT, KSPLIT), dim3(512), 0, stream,
                       x, (const ushort*)d_out, hn, out);
    hipLaunchKernelGGL(gather_kernel, dim3(NN / MT), dim3(512), 0, stream,
                       emb, out);
}